// Round 7
// baseline (570.256 us; speedup 1.0000x reference)
//
#include <hip/hip_runtime.h>
#include <stdint.h>

#define TSTEPS 1024
#define L2E 1.4426950408889634f

typedef float v2f __attribute__((ext_vector_type(2)));
typedef float v4f __attribute__((ext_vector_type(4)));

__device__ __forceinline__ float rcpf_(float v) { return __builtin_amdgcn_rcpf(v); }
__device__ __forceinline__ float ex2(float v) { return __builtin_amdgcn_exp2f(v); }
#define PKFMA(a, b, c) __builtin_elementwise_fma((a), (b), (c))

// quad_perm [1,0,3,2]: exchange with lane^1 — pure VALU
__device__ __forceinline__ float dpp_x1(float v) {
    return __int_as_float(__builtin_amdgcn_update_dpp(
        0, __float_as_int(v), 0xB1, 0xF, 0xF, true));
}
// total of a v2f partial across the lane pair (16 columns)
__device__ __forceinline__ float pairsum(v2f a) {
    float s = a.x + a.y;
    return s + dpp_x1(s);
}

// Opaque loads: value is asm-produced -> cannot be rematerialized as a load.
__device__ __forceinline__ v2f ldg2(const float* p) {
    v2f r; uint64_t a = (uint64_t)p;
    asm volatile("global_load_dwordx2 %0, %1, off\n\ts_waitcnt vmcnt(0)"
                 : "=v"(r) : "v"(a));
    return r;
}
__device__ __forceinline__ float ldg1(const float* p) {
    float r; uint64_t a = (uint64_t)p;
    asm volatile("global_load_dword %0, %1, off\n\ts_waitcnt vmcnt(0)"
                 : "=v"(r) : "v"(a));
    return r;
}

__global__ __launch_bounds__(256, 2) void gru3_pipe(
    const float* __restrict__ x,      // [4096,1024,1]
    const float* __restrict__ w_ih0,  // [48,1]
    const float* __restrict__ w_ih12, // [2,48,16]
    const float* __restrict__ w_hh,   // [3,48,16]
    const float* __restrict__ b_ih,   // [3,48]
    const float* __restrict__ b_hh,   // [3,48]
    const float* __restrict__ fc_w,   // [5,16]
    const float* __restrict__ fc_b,   // [5]
    float* __restrict__ out)          // [4096,5]
{
    __shared__ float xs[8][TSTEPS];  // 32 KB
    __shared__ float hb[8][4][16];   // 2 KB, [grp][layer 0..2 + pad][unit]

    const int l31 = threadIdx.x & 31;  // lane within seq group
    const int grp = threadIdx.x >> 5;  // seq slot in block (0..7)
    const int u = l31 >> 1;            // hidden unit (0..15)
    const int c = l31 & 1;             // column half; partner = lane^1
    const int c8 = c * 8;
    const int seq = blockIdx.x * 8 + grp;

    // ---- stage x (coalesced float4) + zero h buffers
    {
        const float4* xg = (const float4*)(x + (size_t)blockIdx.x * 8 * TSTEPS);
        float4* xs4 = (float4*)&xs[0][0];
#pragma unroll
        for (int j = 0; j < 8; ++j)
            xs4[threadIdx.x + 256 * j] = xg[threadIdx.x + 256 * j];
        ((float*)hb)[threadIdx.x] = 0.f;
        ((float*)hb)[256 + threadIdx.x] = 0.f;
    }

    // ---- weights (asm-pinned), pre-scaled: r/z rows by -L2E (sigmoid via
    // exp2), n rows by 2*L2E (tanh via exp2).
    const float qs[3] = {-L2E, -L2E, 2.f * L2E};
    v2f wh[3][3][4];  // [layer][gate r,z,n][col pair], cols c8..c8+7
    v2f wi[2][3][4];
#pragma unroll
    for (int l = 0; l < 3; ++l)
#pragma unroll
        for (int q = 0; q < 3; ++q)
#pragma unroll
            for (int m = 0; m < 4; ++m)
                wh[l][q][m] =
                    ldg2(w_hh + (l * 48 + q * 16 + u) * 16 + c8 + 2 * m) * qs[q];
#pragma unroll
    for (int l = 0; l < 2; ++l)
#pragma unroll
        for (int q = 0; q < 3; ++q)
#pragma unroll
            for (int m = 0; m < 4; ++m)
                wi[l][q][m] =
                    ldg2(w_ih12 + (l * 48 + q * 16 + u) * 16 + c8 + 2 * m) * qs[q];

    // ---- biases as accumulator seeds (contribute once after pair-reduce)
    v2f bir[3], biz[3], binh[3], binx[2];
#pragma unroll
    for (int l = 0; l < 3; ++l) {
        float vr = -(ldg1(b_ih + l * 48 + u) + ldg1(b_hh + l * 48 + u)) * L2E;
        float vz = -(ldg1(b_ih + l * 48 + 16 + u) + ldg1(b_hh + l * 48 + 16 + u)) * L2E;
        float vn = ldg1(b_hh + l * 48 + 32 + u) * (2.f * L2E);
        bir[l] = (v2f){c ? 0.f : vr, 0.f};
        biz[l] = (v2f){c ? 0.f : vz, 0.f};
        binh[l] = (v2f){c ? 0.f : vn, 0.f};
    }
#pragma unroll
    for (int l = 0; l < 2; ++l) {
        float vx = ldg1(b_ih + (l + 1) * 48 + 32 + u) * (2.f * L2E);
        binx[l] = (v2f){c ? 0.f : vx, 0.f};
    }
    const float bnx0 = ldg1(b_ih + 32 + u) * (2.f * L2E);
    const float wxr = ldg1(w_ih0 + u) * -L2E;
    const float wxz = ldg1(w_ih0 + 16 + u) * -L2E;
    const float wxn = ldg1(w_ih0 + 32 + u) * (2.f * L2E);

    __syncthreads();  // xs + hb ready

    // ---- double-buffered h col-slices (A/B ping-pong across steps)
    v2f hA0[4], hA1[4], hA2[4], hB0[4], hB1[4], hB2[4];
#pragma unroll
    for (int m = 0; m < 4; ++m) {
        hA0[m] = (v2f){0.f, 0.f};
        hA1[m] = (v2f){0.f, 0.f};
        hA2[m] = (v2f){0.f, 0.f};
    }
    float h0o = 0.f, h1o = 0.f, h2o = 0.f;

    const float* xrow = &xs[grp][0];
    float* hw0 = &hb[grp][0][u];
    float* hw1 = &hb[grp][1][u];
    float* hw2 = &hb[grp][2][u];
    const float* hr0 = &hb[grp][0][c8];
    const float* hr1 = &hb[grp][1][c8];
    const float* hr2 = &hb[grp][2][c8];

#define RD4(dst, p)                                                       \
    do {                                                                  \
        v4f ta = *(const v4f*)(p);                                        \
        v4f tb = *(const v4f*)((p) + 4);                                  \
        dst[0] = __builtin_shufflevector(ta, ta, 0, 1);                   \
        dst[1] = __builtin_shufflevector(ta, ta, 2, 3);                   \
        dst[2] = __builtin_shufflevector(tb, tb, 0, 1);                   \
        dst[3] = __builtin_shufflevector(tb, tb, 2, 3);                   \
    } while (0)

// STEP: consume I* (old state), produce O* (fresh readback). Writes and
// readbacks are unconditional (unwritten rows are zero = correct initial h;
// stale rewrites in prolog/epilog are idempotent). Compute is flag-gated.
// Per layer the sigmoid stream is pair-split: c=0 computes sigmoid(r-sum),
// c=1 computes sigmoid(z-sum); DPP + cndmask reconstructs both on both lanes.
#define STEP(I0, I1, I2, O0, O1, O2, F0, F1, F2, XT)                      \
  do {                                                                    \
    v2f a;                                                                \
    if (F0) {                                                             \
      a = PKFMA(wh[0][0][0], I0[0], bir[0]);                              \
      a = PKFMA(wh[0][0][1], I0[1], a);                                   \
      a = PKFMA(wh[0][0][2], I0[2], a);                                   \
      a = PKFMA(wh[0][0][3], I0[3], a);                                   \
      float sr = fmaf(wxr, (XT), pairsum(a));                             \
      a = PKFMA(wh[0][1][0], I0[0], biz[0]);                              \
      a = PKFMA(wh[0][1][1], I0[1], a);                                   \
      a = PKFMA(wh[0][1][2], I0[2], a);                                   \
      a = PKFMA(wh[0][1][3], I0[3], a);                                   \
      float sz = fmaf(wxz, (XT), pairsum(a));                             \
      a = PKFMA(wh[0][2][0], I0[0], binh[0]);                             \
      a = PKFMA(wh[0][2][1], I0[1], a);                                   \
      a = PKFMA(wh[0][2][2], I0[2], a);                                   \
      a = PKFMA(wh[0][2][3], I0[3], a);                                   \
      float sn = pairsum(a);                                              \
      float p = c ? sz : sr;                                              \
      float sg = rcpf_(1.f + ex2(p));                                     \
      float og = dpp_x1(sg);                                              \
      float r = c ? og : sg;                                              \
      float z = c ? sg : og;                                              \
      float ut = fmaf(r, sn, fmaf(wxn, (XT), bnx0));                      \
      float n = fmaf(-2.f, rcpf_(ex2(ut) + 1.f), 1.f);                    \
      h0o = fmaf(z, h0o - n, n);                                          \
    }                                                                     \
    *hw0 = h0o;                                                           \
    RD4(O0, hr0);                                                         \
    if (F1) {                                                             \
      a = PKFMA(wh[1][0][0], I1[0], bir[1]);                              \
      a = PKFMA(wh[1][0][1], I1[1], a);                                   \
      a = PKFMA(wh[1][0][2], I1[2], a);                                   \
      a = PKFMA(wh[1][0][3], I1[3], a);                                   \
      a = PKFMA(wi[0][0][0], I0[0], a);                                   \
      a = PKFMA(wi[0][0][1], I0[1], a);                                   \
      a = PKFMA(wi[0][0][2], I0[2], a);                                   \
      a = PKFMA(wi[0][0][3], I0[3], a);                                   \
      float sr = pairsum(a);                                              \
      a = PKFMA(wh[1][1][0], I1[0], biz[1]);                              \
      a = PKFMA(wh[1][1][1], I1[1], a);                                   \
      a = PKFMA(wh[1][1][2], I1[2], a);                                   \
      a = PKFMA(wh[1][1][3], I1[3], a);                                   \
      a = PKFMA(wi[0][1][0], I0[0], a);                                   \
      a = PKFMA(wi[0][1][1], I0[1], a);                                   \
      a = PKFMA(wi[0][1][2], I0[2], a);                                   \
      a = PKFMA(wi[0][1][3], I0[3], a);                                   \
      float sz = pairsum(a);                                              \
      a = PKFMA(wh[1][2][0], I1[0], binh[1]);                             \
      a = PKFMA(wh[1][2][1], I1[1], a);                                   \
      a = PKFMA(wh[1][2][2], I1[2], a);                                   \
      a = PKFMA(wh[1][2][3], I1[3], a);                                   \
      float snh = pairsum(a);                                             \
      a = PKFMA(wi[0][2][0], I0[0], binx[0]);                             \
      a = PKFMA(wi[0][2][1], I0[1], a);                                   \
      a = PKFMA(wi[0][2][2], I0[2], a);                                   \
      a = PKFMA(wi[0][2][3], I0[3], a);                                   \
      float snx = pairsum(a);                                             \
      float p = c ? sz : sr;                                              \
      float sg = rcpf_(1.f + ex2(p));                                     \
      float og = dpp_x1(sg);                                              \
      float r = c ? og : sg;                                              \
      float z = c ? sg : og;                                              \
      float ut = fmaf(r, snh, snx);                                       \
      float n = fmaf(-2.f, rcpf_(ex2(ut) + 1.f), 1.f);                    \
      h1o = fmaf(z, h1o - n, n);                                          \
    }                                                                     \
    *hw1 = h1o;                                                           \
    RD4(O1, hr1);                                                         \
    if (F2) {                                                             \
      a = PKFMA(wh[2][0][0], I2[0], bir[2]);                              \
      a = PKFMA(wh[2][0][1], I2[1], a);                                   \
      a = PKFMA(wh[2][0][2], I2[2], a);                                   \
      a = PKFMA(wh[2][0][3], I2[3], a);                                   \
      a = PKFMA(wi[1][0][0], I1[0], a);                                   \
      a = PKFMA(wi[1][0][1], I1[1], a);                                   \
      a = PKFMA(wi[1][0][2], I1[2], a);                                   \
      a = PKFMA(wi[1][0][3], I1[3], a);                                   \
      float sr = pairsum(a);                                              \
      a = PKFMA(wh[2][1][0], I2[0], biz[2]);                              \
      a = PKFMA(wh[2][1][1], I2[1], a);                                   \
      a = PKFMA(wh[2][1][2], I2[2], a);                                   \
      a = PKFMA(wh[2][1][3], I2[3], a);                                   \
      a = PKFMA(wi[1][1][0], I1[0], a);                                   \
      a = PKFMA(wi[1][1][1], I1[1], a);                                   \
      a = PKFMA(wi[1][1][2], I1[2], a);                                   \
      a = PKFMA(wi[1][1][3], I1[3], a);                                   \
      float sz = pairsum(a);                                              \
      a = PKFMA(wh[2][2][0], I2[0], binh[2]);                             \
      a = PKFMA(wh[2][2][1], I2[1], a);                                   \
      a = PKFMA(wh[2][2][2], I2[2], a);                                   \
      a = PKFMA(wh[2][2][3], I2[3], a);                                   \
      float snh = pairsum(a);                                             \
      a = PKFMA(wi[1][2][0], I1[0], binx[1]);                             \
      a = PKFMA(wi[1][2][1], I1[1], a);                                   \
      a = PKFMA(wi[1][2][2], I1[2], a);                                   \
      a = PKFMA(wi[1][2][3], I1[3], a);                                   \
      float snx = pairsum(a);                                             \
      float p = c ? sz : sr;                                              \
      float sg = rcpf_(1.f + ex2(p));                                     \
      float og = dpp_x1(sg);                                              \
      float r = c ? og : sg;                                              \
      float z = c ? sg : og;                                              \
      float ut = fmaf(r, snh, snx);                                       \
      float n = fmaf(-2.f, rcpf_(ex2(ut) + 1.f), 1.f);                    \
      h2o = fmaf(z, h2o - n, n);                                          \
    }                                                                     \
    *hw2 = h2o;                                                           \
    RD4(O2, hr2);                                                         \
  } while (0)

    // ---- diagonal schedule: iter t0 computes L0(t0), L1(t0-1), L2(t0-2)
    STEP(hA0, hA1, hA2, hB0, hB1, hB2, true, false, false, xrow[0]);
    STEP(hB0, hB1, hB2, hA0, hA1, hA2, true, true, false, xrow[1]);
    for (int t0 = 2; t0 < TSTEPS; t0 += 2) {
        v2f x2 = *(const v2f*)&xrow[t0];  // one b64 read per 2 steps
        STEP(hA0, hA1, hA2, hB0, hB1, hB2, true, true, true, x2.x);
        STEP(hB0, hB1, hB2, hA0, hA1, hA2, true, true, true, x2.y);
    }
    STEP(hA0, hA1, hA2, hB0, hB1, hB2, false, true, true, 0.f);
    STEP(hB0, hB1, hB2, hA0, hA1, hA2, false, false, true, 0.f);

    // ---- head on h2(1023) (in hb[grp][2][*])
    if (l31 < 5) {
        float acc = fc_b[l31];
#pragma unroll
        for (int j = 0; j < 16; ++j)
            acc = fmaf(fc_w[l31 * 16 + j], hb[grp][2][j], acc);
        out[seq * 5 + l31] = acc;
    }
#undef RD4
#undef STEP
}

extern "C" void kernel_launch(void* const* d_in, const int* in_sizes, int n_in,
                              void* d_out, int out_size, void* d_ws, size_t ws_size,
                              hipStream_t stream) {
    const float* x      = (const float*)d_in[0];
    const float* w_ih0  = (const float*)d_in[1];
    const float* w_ih12 = (const float*)d_in[2];
    const float* w_hh   = (const float*)d_in[3];
    const float* b_ih   = (const float*)d_in[4];
    const float* b_hh   = (const float*)d_in[5];
    const float* fc_w   = (const float*)d_in[6];
    const float* fc_b   = (const float*)d_in[7];
    float* out = (float*)d_out;

    // 4096 seqs x 32 lanes = 131072 threads = 2048 waves = 2 waves/SIMD
    gru3_pipe<<<512, 256, 0, stream>>>(
        x, w_ih0, w_ih12, w_hh, b_ih, b_hh, fc_w, fc_b, out);
}

// Round 8
// 540.361 us; speedup vs baseline: 1.0553x; 1.0553x over previous
//
#include <hip/hip_runtime.h>
#include <stdint.h>

#define TSTEPS 1024
#define L2E 1.4426950408889634f

typedef float v2f __attribute__((ext_vector_type(2)));
typedef float v4f __attribute__((ext_vector_type(4)));

__device__ __forceinline__ float rcpf_(float v) { return __builtin_amdgcn_rcpf(v); }
__device__ __forceinline__ float ex2(float v) { return __builtin_amdgcn_exp2f(v); }
#define PKFMA(a, b, c) __builtin_elementwise_fma((a), (b), (c))

// quad_perm [1,0,3,2]: exchange with lane^1 — pure VALU
__device__ __forceinline__ float dpp_x1(float v) {
    return __int_as_float(__builtin_amdgcn_update_dpp(
        0, __float_as_int(v), 0xB1, 0xF, 0xF, true));
}
// total of a v2f partial across the lane pair (16 columns)
__device__ __forceinline__ float pairsum(v2f a) {
    float s = a.x + a.y;
    return s + dpp_x1(s);
}

// Opaque loads: value is asm-produced -> cannot be rematerialized as a load.
__device__ __forceinline__ v2f ldg2(const float* p) {
    v2f r; uint64_t a = (uint64_t)p;
    asm volatile("global_load_dwordx2 %0, %1, off\n\ts_waitcnt vmcnt(0)"
                 : "=v"(r) : "v"(a));
    return r;
}
__device__ __forceinline__ float ldg1(const float* p) {
    float r; uint64_t a = (uint64_t)p;
    asm volatile("global_load_dword %0, %1, off\n\ts_waitcnt vmcnt(0)"
                 : "=v"(r) : "v"(a));
    return r;
}

// 4-term and 8-term pk-FMA dot chains
#define CH4(W, H, SEED) \
    PKFMA(W[3], H[3], PKFMA(W[2], H[2], PKFMA(W[1], H[1], PKFMA(W[0], H[0], (SEED)))))
#define CH8(Wa, Ha, Wb, Hb, SEED) CH4(Wa, Ha, CH4(Wb, Hb, (SEED)))

__global__ __launch_bounds__(256, 2) void gru3_tp(
    const float* __restrict__ x,      // [4096,1024,1]
    const float* __restrict__ w_ih0,  // [48,1]
    const float* __restrict__ w_ih12, // [2,48,16]
    const float* __restrict__ w_hh,   // [3,48,16]
    const float* __restrict__ b_ih,   // [3,48]
    const float* __restrict__ b_hh,   // [3,48]
    const float* __restrict__ fc_w,   // [5,16]
    const float* __restrict__ fc_b,   // [5]
    float* __restrict__ out)          // [4096,5]
{
    __shared__ float xs[8][TSTEPS];  // 32 KB
    __shared__ float hb[8][4][16];   // [grp][layer 0..2 + pad][unit]

    const int l31 = threadIdx.x & 31;  // lane within seq group
    const int grp = threadIdx.x >> 5;  // seq slot in block (0..7)
    const int u = l31 >> 1;            // hidden unit (0..15)
    const int c = l31 & 1;             // column half / role; partner = lane^1
    const int c8 = c * 8;
    const int seq = blockIdx.x * 8 + grp;

    // ---- stage x (coalesced float4) + zero h buffers
    {
        const float4* xg = (const float4*)(x + (size_t)blockIdx.x * 8 * TSTEPS);
        float4* xs4 = (float4*)&xs[0][0];
#pragma unroll
        for (int j = 0; j < 8; ++j)
            xs4[threadIdx.x + 256 * j] = xg[threadIdx.x + 256 * j];
        ((float*)hb)[threadIdx.x] = 0.f;
        ((float*)hb)[256 + threadIdx.x] = 0.f;
    }

    // ---- weights (asm-pinned), pre-scaled: r/z rows by -L2E (sigmoid via
    // exp2), n rows by 2*L2E (tanh via exp2).
    const float qs[3] = {-L2E, -L2E, 2.f * L2E};
    v2f wh[3][3][4];  // [layer][gate r,z,n][col pair], cols c8..c8+7
    v2f wi[2][3][4];
#pragma unroll
    for (int l = 0; l < 3; ++l)
#pragma unroll
        for (int q = 0; q < 3; ++q)
#pragma unroll
            for (int m = 0; m < 4; ++m)
                wh[l][q][m] =
                    ldg2(w_hh + (l * 48 + q * 16 + u) * 16 + c8 + 2 * m) * qs[q];
#pragma unroll
    for (int l = 0; l < 2; ++l)
#pragma unroll
        for (int q = 0; q < 3; ++q)
#pragma unroll
            for (int m = 0; m < 4; ++m)
                wi[l][q][m] =
                    ldg2(w_ih12 + (l * 48 + q * 16 + u) * 16 + c8 + 2 * m) * qs[q];

    // ---- biases as accumulator seeds (contribute once: c=0 lane, .x half)
    v2f bir[3], biz[3], binh[3], binx[2];
#pragma unroll
    for (int l = 0; l < 3; ++l) {
        float vr = -(ldg1(b_ih + l * 48 + u) + ldg1(b_hh + l * 48 + u)) * L2E;
        float vz = -(ldg1(b_ih + l * 48 + 16 + u) + ldg1(b_hh + l * 48 + 16 + u)) * L2E;
        float vn = ldg1(b_hh + l * 48 + 32 + u) * (2.f * L2E);
        bir[l] = (v2f){c ? 0.f : vr, 0.f};
        biz[l] = (v2f){c ? 0.f : vz, 0.f};
        binh[l] = (v2f){c ? 0.f : vn, 0.f};
    }
#pragma unroll
    for (int l = 0; l < 2; ++l) {
        float vx = ldg1(b_ih + (l + 1) * 48 + 32 + u) * (2.f * L2E);
        binx[l] = (v2f){c ? 0.f : vx, 0.f};
    }
    const float bnx0 = ldg1(b_ih + 32 + u) * (2.f * L2E);
    const float wxr = ldg1(w_ih0 + u) * -L2E;
    const float wxz = ldg1(w_ih0 + 16 + u) * -L2E;
    const float wxn = ldg1(w_ih0 + 32 + u) * (2.f * L2E);

    __syncthreads();  // xs + hb ready

    // ---- state: per-lane col slices + role-packed own h (c=0: h0[u], c=1: h1[u])
    v2f h0s[4], h1s[4], h2s[4];
#pragma unroll
    for (int m = 0; m < 4; ++m) {
        h0s[m] = (v2f){0.f, 0.f};
        h1s[m] = (v2f){0.f, 0.f};
        h2s[m] = (v2f){0.f, 0.f};
    }
    float h01o = 0.f;  // own h: layer c, unit u
    float h2o = 0.f;   // own h2[u] (both pair lanes)

    const float* xrow = &xs[grp][0];
    float* hw01 = &hb[grp][c][u];   // role write: c=0 -> h0 row, c=1 -> h1 row
    float* hw2 = &hb[grp][2][u];
    const float* hr0 = &hb[grp][0][c8];
    const float* hr1 = &hb[grp][1][c8];
    const float* hr2 = &hb[grp][2][c8];

#define RD4(dst, p)                                                       \
    do {                                                                  \
        v4f ta = *(const v4f*)(p);                                        \
        v4f tb = *(const v4f*)((p) + 4);                                  \
        dst[0] = __builtin_shufflevector(ta, ta, 0, 1);                   \
        dst[1] = __builtin_shufflevector(ta, ta, 2, 3);                   \
        dst[2] = __builtin_shufflevector(tb, tb, 0, 1);                   \
        dst[3] = __builtin_shufflevector(tb, tb, 2, 3);                   \
    } while (0)

    // One diagonal iteration: L0 at t0, L1 at t0-1, L2 at t0-2 (independent).
    // Sigmoid passes are pair-split (c=0: sigma(r), c=1: sigma(z), DPP swap).
    // L0/L1 tanh+update packed: c=0 runs L0's n-gate + h0 update, c=1 runs L1's.
    auto step = [&](bool F0, bool F1, bool F2, float xt) {
        float sg0 = 0.f, og0 = 0.f, sg1 = 0.f, og1 = 0.f;
        float snh0 = 0.f, snx0 = 0.f, snh1 = 0.f, snx1 = 0.f;
        if (F0) {
            float sr = fmaf(wxr, xt, pairsum(CH4(wh[0][0], h0s, bir[0])));
            float sz = fmaf(wxz, xt, pairsum(CH4(wh[0][1], h0s, biz[0])));
            float p = c ? sz : sr;
            sg0 = rcpf_(1.f + ex2(p));   // c=0: r0, c=1: z0
            og0 = dpp_x1(sg0);           // c=0: z0, c=1: r0
            snh0 = pairsum(CH4(wh[0][2], h0s, binh[0]));
            snx0 = fmaf(wxn, xt, bnx0);
        }
        if (F1) {
            float sr = pairsum(CH8(wh[1][0], h1s, wi[0][0], h0s, bir[1]));
            float sz = pairsum(CH8(wh[1][1], h1s, wi[0][1], h0s, biz[1]));
            float p = c ? sz : sr;
            sg1 = rcpf_(1.f + ex2(p));   // c=0: r1, c=1: z1
            og1 = dpp_x1(sg1);           // c=0: z1, c=1: r1
            snh1 = pairsum(CH4(wh[1][2], h1s, binh[1]));
            snx1 = pairsum(CH4(wi[0][2], h0s, binx[0]));
        }
        if (F0 || F1) {
            // packed n-gate: lane role c picks its layer
            float rsel = c ? og1 : sg0;   // r_{Lc}
            float zsel = c ? sg1 : og0;   // z_{Lc}
            float snh = c ? snh1 : snh0;
            float snx = c ? snx1 : snx0;
            float ut = fmaf(rsel, snh, snx);
            float n = fmaf(-2.f, rcpf_(ex2(ut) + 1.f), 1.f);
            float hn = fmaf(zsel, h01o - n, n);
            bool act = c ? F1 : F0;       // compile-time folds in steady state
            h01o = act ? hn : h01o;
        }
        *hw01 = h01o;  // c=0 writes h0 row, c=1 writes h1 row (one ds_write)
        if (F2) {
            float sr = pairsum(CH8(wh[2][0], h2s, wi[1][0], h1s, bir[2]));
            float sz = pairsum(CH8(wh[2][1], h2s, wi[1][1], h1s, biz[2]));
            float p = c ? sz : sr;
            float sg = rcpf_(1.f + ex2(p));
            float og = dpp_x1(sg);
            float r2 = c ? og : sg;
            float z2 = c ? sg : og;
            float snh = pairsum(CH4(wh[2][2], h2s, binh[2]));
            float snx = pairsum(CH4(wi[1][2], h1s, binx[1]));
            float ut = fmaf(r2, snh, snx);
            float n = fmaf(-2.f, rcpf_(ex2(ut) + 1.f), 1.f);
            h2o = fmaf(z2, h2o - n, n);
        }
        *hw2 = h2o;
        // readback fresh slices (same-wave DS ops are program-ordered)
        RD4(h0s, hr0);
        RD4(h1s, hr1);
        RD4(h2s, hr2);
    };

    // ---- diagonal schedule with x prefetched one iteration ahead
    v2f xc = *(const v2f*)&xrow[0];
    step(true, false, false, xc.x);   // t0 = 0
    step(true, true, false, xc.y);    // t0 = 1
    v2f xn = *(const v2f*)&xrow[2];
    for (int t0 = 2; t0 < TSTEPS; t0 += 2) {
        xc = xn;
        xn = *(const v2f*)&xrow[(t0 + 2) & (TSTEPS - 1)];  // next-iter prefetch
        step(true, true, true, xc.x);
        step(true, true, true, xc.y);
    }
    step(false, true, true, 0.f);     // drain L1, L2
    step(false, false, true, 0.f);    // drain L2

    // ---- head on h2(1023) (in hb[grp][2][*])
    if (l31 < 5) {
        float acc = fc_b[l31];
#pragma unroll
        for (int j = 0; j < 16; ++j)
            acc = fmaf(fc_w[l31 * 16 + j], hb[grp][2][j], acc);
        out[seq * 5 + l31] = acc;
    }
#undef RD4
}

extern "C" void kernel_launch(void* const* d_in, const int* in_sizes, int n_in,
                              void* d_out, int out_size, void* d_ws, size_t ws_size,
                              hipStream_t stream) {
    const float* x      = (const float*)d_in[0];
    const float* w_ih0  = (const float*)d_in[1];
    const float* w_ih12 = (const float*)d_in[2];
    const float* w_hh   = (const float*)d_in[3];
    const float* b_ih   = (const float*)d_in[4];
    const float* b_hh   = (const float*)d_in[5];
    const float* fc_w   = (const float*)d_in[6];
    const float* fc_b   = (const float*)d_in[7];
    float* out = (float*)d_out;

    // 4096 seqs x 32 lanes = 131072 threads = 2048 waves = 2 waves/SIMD
    gru3_tp<<<512, 256, 0, stream>>>(
        x, w_ih0, w_ih12, w_hh, b_ih, b_hh, fc_w, fc_b, out);
}